// Round 1
// baseline (319.551 us; speedup 1.0000x reference)
//
#include <hip/hip_runtime.h>
#include <stdint.h>

typedef unsigned short u16;
typedef unsigned int u32;
typedef __attribute__((ext_vector_type(8))) short s16x8;
typedef __attribute__((ext_vector_type(8))) __bf16 bf16x8;
typedef __attribute__((ext_vector_type(4))) float f32x4;
typedef __attribute__((ext_vector_type(4))) u16 u16x4;

#define L_TOT 32768
#define ITER 8

__device__ __forceinline__ u32 f2bf(float f){
  u32 u = __builtin_bit_cast(u32, f);
  return (u + 0x7FFFu + ((u >> 16) & 1u)) >> 16;
}
// XOR swizzle: flips byte-addr bits 4-6 with row bits (row stride 256B, 8-row period).
__device__ __forceinline__ u32 swz(u32 a){ return a ^ (((a >> 8) & 7u) << 4); }

__device__ __forceinline__ f32x4 mfma16(s16x8 a, s16x8 b, f32x4 c){
  return __builtin_amdgcn_mfma_f32_16x16x32_bf16(
      __builtin_bit_cast(bf16x8, a), __builtin_bit_cast(bf16x8, b), c, 0, 0, 0);
}

__device__ __forceinline__ void gload16(const void* g, void* l){
  __builtin_amdgcn_global_load_lds(
      (const __attribute__((address_space(1))) void*)g,
      (__attribute__((address_space(3))) void*)l, 16, 0, 0);
}

// ---------------- prep: v -> bf16, Wk/Wv -> transposed bf16 [hd][cin] ----------------
__global__ void kprep(const float* __restrict__ v, const float* __restrict__ Wk,
                      const float* __restrict__ Wv, u16* __restrict__ X,
                      u16* __restrict__ WkT, u16* __restrict__ WvT){
  int tid = blockIdx.x * blockDim.x + threadIdx.x;
  int stride = gridDim.x * blockDim.x;
  for (int i = tid; i < 2097152; i += stride){
    float4 f = *((const float4*)v + i);
    u16x4 o; o.x = (u16)f2bf(f.x); o.y = (u16)f2bf(f.y); o.z = (u16)f2bf(f.z); o.w = (u16)f2bf(f.w);
    *((u16x4*)X + i) = o;
  }
  for (int i = tid; i < 131072; i += stride){
    int n = i >> 7, c = i & 127;
    WkT[i] = (u16)f2bf(Wk[c * 1024 + n]);
    WvT[i] = (u16)f2bf(Wv[c * 1024 + n]);
  }
}

// --------- fused K/V projection + per-head LN + AM += K^T V (per b,h) ---------
__device__ __forceinline__ void proj_ln_store(
    const char* sW, char* sT, const s16x8 (&af)[2][4],
    const float (&br)[8], const float (&gr)[8], const float (&betar)[8],
    int wid, int g, int l15)
{
  f32x4 acc[2][8];
  #pragma unroll
  for (int mt = 0; mt < 2; ++mt)
    #pragma unroll
    for (int nt = 0; nt < 8; ++nt) acc[mt][nt] = f32x4{0.f, 0.f, 0.f, 0.f};

  #pragma unroll
  for (int ks = 0; ks < 4; ++ks){
    #pragma unroll
    for (int nt = 0; nt < 8; ++nt){
      u32 a = (u32)((nt * 16 + l15) * 256 + ks * 64 + g * 16);
      s16x8 bf = *(const s16x8*)(sW + swz(a));
      acc[0][nt] = mfma16(af[0][ks], bf, acc[0][nt]);
      acc[1][nt] = mfma16(af[1][ks], bf, acc[1][nt]);
    }
  }
  #pragma unroll
  for (int mt = 0; mt < 2; ++mt){
    #pragma unroll
    for (int j = 0; j < 4; ++j){
      float s = 0.f, q = 0.f;
      float vv[8];
      #pragma unroll
      for (int nt = 0; nt < 8; ++nt){
        float t = acc[mt][nt][j] + br[nt];
        vv[nt] = t; s += t; q += t * t;
      }
      s += __shfl_xor(s, 1); s += __shfl_xor(s, 2); s += __shfl_xor(s, 4); s += __shfl_xor(s, 8);
      q += __shfl_xor(q, 1); q += __shfl_xor(q, 2); q += __shfl_xor(q, 4); q += __shfl_xor(q, 8);
      float mean = s * 0.0078125f;
      float var  = q * 0.0078125f - mean * mean;
      float rstd = rsqrtf(var + 1e-5f);
      #pragma unroll
      for (int nt = 0; nt < 8; ++nt)
        acc[mt][nt][j] = (vv[nt] - mean) * rstd * gr[nt] + betar[nt];
    }
    #pragma unroll
    for (int nt = 0; nt < 8; ++nt){
      int dk = nt * 16 + l15;
      int lc = wid * 32 + mt * 16 + g * 4;
      u32 base = (u32)(dk * 256 + lc * 2);
      u32 w01 = f2bf(acc[mt][nt][0]) | (f2bf(acc[mt][nt][1]) << 16);
      u32 w23 = f2bf(acc[mt][nt][2]) | (f2bf(acc[mt][nt][3]) << 16);
      *(u32*)(sT + swz(base))     = w01;
      *(u32*)(sT + swz(base + 4)) = w23;
    }
  }
}

__global__ __launch_bounds__(256, 1) void kattn(
    const u16* __restrict__ X, const u16* __restrict__ WkT, const u16* __restrict__ WvT,
    const float* __restrict__ bk, const float* __restrict__ bv,
    const float* __restrict__ gk, const float* __restrict__ bbk,
    const float* __restrict__ gv, const float* __restrict__ bbv,
    float* __restrict__ AM)
{
  extern __shared__ char smem[];
  char* sWk = smem;            // 32 KiB, [dk][c] swizzled
  char* sWv = smem + 32768;
  char* sKT = smem + 65536;    // [dk][l] swizzled
  char* sVT = smem + 98304;    // [dv][l] swizzled

  const int tid = threadIdx.x;
  const int wid = tid >> 6, lane = tid & 63, g = lane >> 4, l15 = lane & 15;
  const int bh = blockIdx.x >> 5, grp = blockIdx.x & 31;
  const int b = bh >> 3, h = bh & 7;

  { // stage head weight slices (contiguous 32KB each), pre-swizzled source
    const char* gwk = (const char*)(WkT + h * 16384);
    const char* gwv = (const char*)(WvT + h * 16384);
    #pragma unroll
    for (int call = 0; call < 8; ++call){
      u32 o = (u32)(call * 4096 + wid * 1024 + lane * 16);
      gload16(gwk + swz(o), sWk + (call * 4096 + wid * 1024));
      gload16(gwv + swz(o), sWv + (call * 4096 + wid * 1024));
    }
  }
  float bk_r[8], gk_r[8], bbk_r[8], bv_r[8], gv_r[8], bbv_r[8];
  #pragma unroll
  for (int nt = 0; nt < 8; ++nt){
    int idx = h * 128 + nt * 16 + l15;
    bk_r[nt] = bk[idx]; gk_r[nt] = gk[idx]; bbk_r[nt] = bbk[idx];
    bv_r[nt] = bv[idx]; gv_r[nt] = gv[idx]; bbv_r[nt] = bbv[idx];
  }
  asm volatile("s_waitcnt vmcnt(0)" ::: "memory");
  __syncthreads();

  f32x4 am[2][8];
  #pragma unroll
  for (int mt = 0; mt < 2; ++mt)
    #pragma unroll
    for (int nt = 0; nt < 8; ++nt) am[mt][nt] = f32x4{0.f, 0.f, 0.f, 0.f};

  const u16* Xb = X + (size_t)b * (L_TOT * 128);

  for (int it = 0; it < ITER; ++it){
    int chunk = grp * ITER + it;
    int row0 = chunk * 128;
    s16x8 af[2][4];
    #pragma unroll
    for (int mt = 0; mt < 2; ++mt)
      #pragma unroll
      for (int ks = 0; ks < 4; ++ks){
        int r = row0 + wid * 32 + mt * 16 + l15;
        af[mt][ks] = *(const s16x8*)(Xb + (size_t)r * 128 + ks * 32 + g * 8);
      }

    proj_ln_store(sWk, sKT, af, bk_r, gk_r, bbk_r, wid, g, l15);
    proj_ln_store(sWv, sVT, af, bv_r, gv_r, bbv_r, wid, g, l15);
    __syncthreads();

    #pragma unroll
    for (int ks2 = 0; ks2 < 4; ++ks2){
      s16x8 a2[2];
      #pragma unroll
      for (int mt2 = 0; mt2 < 2; ++mt2){
        int dk = wid * 32 + mt2 * 16 + l15;
        u32 a = (u32)(dk * 256 + ks2 * 64 + g * 16);
        a2[mt2] = *(const s16x8*)(sKT + swz(a));
      }
      #pragma unroll
      for (int nt = 0; nt < 8; ++nt){
        int dv = nt * 16 + l15;
        u32 aa = (u32)(dv * 256 + ks2 * 64 + g * 16);
        s16x8 b2 = *(const s16x8*)(sVT + swz(aa));
        am[0][nt] = mfma16(a2[0], b2, am[0][nt]);
        am[1][nt] = mfma16(a2[1], b2, am[1][nt]);
      }
    }
    __syncthreads();
  }

  float* AMbh = AM + (size_t)bh * 16384;
  #pragma unroll
  for (int mt = 0; mt < 2; ++mt)
    #pragma unroll
    for (int nt = 0; nt < 8; ++nt)
      #pragma unroll
      for (int j = 0; j < 4; ++j){
        int dk = wid * 32 + mt * 16 + g * 4 + j;
        int dv = nt * 16 + l15;
        atomicAdd(AMbh + dk * 128 + dv, am[mt][nt][j]);
      }
}

// --------- fold: tmp = blockdiag(AM) @ Wo ; W4 = Wq @ tmp / n ; c4 bias ---------
__global__ void kfold1(const float* __restrict__ AM, const float* __restrict__ Wo,
                       float* __restrict__ tmp){
  int bh = blockIdx.x; int b = bh >> 3, h = bh & 7;
  int tid = threadIdx.x;
  int r0 = (tid >> 4) * 8, e0 = (tid & 15) * 8;
  float acc[8][8] = {};
  const float* AMb = AM + (size_t)bh * 16384;
  const float* Woh = Wo + (size_t)h * 16384;
  for (int c = 0; c < 128; ++c){
    float av[8], wv[8];
    #pragma unroll
    for (int i = 0; i < 8; ++i) av[i] = AMb[(r0 + i) * 128 + c];
    #pragma unroll
    for (int j = 0; j < 8; ++j) wv[j] = Woh[c * 128 + e0 + j];
    #pragma unroll
    for (int i = 0; i < 8; ++i)
      #pragma unroll
      for (int j = 0; j < 8; ++j) acc[i][j] += av[i] * wv[j];
  }
  float* tb = tmp + (size_t)b * 131072 + (size_t)(h * 128 + r0) * 128;
  #pragma unroll
  for (int i = 0; i < 8; ++i)
    #pragma unroll
    for (int j = 0; j < 8; ++j) tb[i * 128 + e0 + j] = acc[i][j];
}

__global__ void kfold2(const float* __restrict__ Wq, const float* __restrict__ Wq_b,
                       const float* __restrict__ Wo_b, const float* __restrict__ tmp,
                       float* __restrict__ W4, float* __restrict__ c4){
  int id = blockIdx.x; int b = id >> 3, hs = id & 7;
  int tid = threadIdx.x;
  int r0 = (tid >> 4) * 8, e0 = (tid & 15) * 8;
  float acc[8][8] = {};
  const float* tb = tmp + (size_t)b * 131072 + (size_t)hs * 16384;
  for (int d = 0; d < 128; ++d){
    float wq[8], tv[8];
    #pragma unroll
    for (int i = 0; i < 8; ++i) wq[i] = Wq[(size_t)(r0 + i) * 1024 + hs * 128 + d];
    #pragma unroll
    for (int j = 0; j < 8; ++j) tv[j] = tb[d * 128 + e0 + j];
    #pragma unroll
    for (int i = 0; i < 8; ++i)
      #pragma unroll
      for (int j = 0; j < 8; ++j) acc[i][j] += wq[i] * tv[j];
  }
  const float inv_n = 0.0009765625f; // 1/1024
  #pragma unroll
  for (int i = 0; i < 8; ++i)
    #pragma unroll
    for (int j = 0; j < 8; ++j)
      atomicAdd(W4 + (size_t)b * 16384 + (r0 + i) * 128 + e0 + j, acc[i][j] * inv_n);
  if (tid < 128){
    float s = 0.f;
    for (int d = 0; d < 128; ++d) s += Wq_b[hs * 128 + d] * tb[d * 128 + tid];
    if (hs == 0) s += Wo_b[tid];
    atomicAdd(c4 + b * 128 + tid, s * inv_n);
  }
}

__global__ void kfold3(const float* __restrict__ W4, u16* __restrict__ W4T){
  int i = blockIdx.x * 256 + threadIdx.x;
  if (i >= 32768) return;
  int b = i >> 14, r = i & 16383, e = r >> 7, c = r & 127;
  W4T[i] = (u16)f2bf(W4[(size_t)b * 16384 + c * 128 + e]);
}

// ---------------- out = x @ W4[b] + c4[b] ----------------
__global__ __launch_bounds__(256, 2) void kout(
    const u16* __restrict__ X, const u16* __restrict__ W4T,
    const float* __restrict__ c4, float* __restrict__ out)
{
  extern __shared__ char smem[];
  char* sX = smem; char* sW = smem + 32768;
  int tid = threadIdx.x, wid = tid >> 6, lane = tid & 63, g = lane >> 4, l15 = lane & 15;
  int blk = blockIdx.x; int b = blk >> 8, ch = blk & 255;
  const char* gx = (const char*)(X + ((size_t)b * L_TOT + ch * 128) * 128);
  const char* gw = (const char*)(W4T + (size_t)b * 16384);
  #pragma unroll
  for (int call = 0; call < 8; ++call){
    u32 o = (u32)(call * 4096 + wid * 1024 + lane * 16);
    gload16(gx + swz(o), sX + (call * 4096 + wid * 1024));
    gload16(gw + swz(o), sW + (call * 4096 + wid * 1024));
  }
  asm volatile("s_waitcnt vmcnt(0)" ::: "memory");
  __syncthreads();

  f32x4 acc[2][8];
  #pragma unroll
  for (int mt = 0; mt < 2; ++mt)
    #pragma unroll
    for (int nt = 0; nt < 8; ++nt) acc[mt][nt] = f32x4{0.f, 0.f, 0.f, 0.f};

  #pragma unroll
  for (int ks = 0; ks < 4; ++ks){
    s16x8 a0, a1;
    {
      int r = wid * 32 + l15;
      a0 = *(const s16x8*)(sX + swz((u32)(r * 256 + ks * 64 + g * 16)));
      a1 = *(const s16x8*)(sX + swz((u32)((r + 16) * 256 + ks * 64 + g * 16)));
    }
    #pragma unroll
    for (int nt = 0; nt < 8; ++nt){
      int e = nt * 16 + l15;
      s16x8 bfr = *(const s16x8*)(sW + swz((u32)(e * 256 + ks * 64 + g * 16)));
      acc[0][nt] = mfma16(a0, bfr, acc[0][nt]);
      acc[1][nt] = mfma16(a1, bfr, acc[1][nt]);
    }
  }
  float* ob = out + ((size_t)b * L_TOT + ch * 128) * 128;
  #pragma unroll
  for (int nt = 0; nt < 8; ++nt){
    float c4v = c4[b * 128 + nt * 16 + l15];
    #pragma unroll
    for (int mt = 0; mt < 2; ++mt)
      #pragma unroll
      for (int j = 0; j < 4; ++j){
        int r = wid * 32 + mt * 16 + g * 4 + j;
        ob[r * 128 + nt * 16 + l15] = acc[mt][nt][j] + c4v;
      }
  }
}

extern "C" void kernel_launch(void* const* d_in, const int* in_sizes, int n_in,
                              void* d_out, int out_size, void* d_ws, size_t ws_size,
                              hipStream_t stream){
  const float* v    = (const float*)d_in[0];
  const float* Wq_w = (const float*)d_in[1];
  const float* Wq_b = (const float*)d_in[2];
  const float* Wk_w = (const float*)d_in[3];
  const float* Wk_b = (const float*)d_in[4];
  const float* Wv_w = (const float*)d_in[5];
  const float* Wv_b = (const float*)d_in[6];
  const float* Wo_w = (const float*)d_in[7];
  const float* Wo_b = (const float*)d_in[8];
  const float* lnk_g = (const float*)d_in[9];
  const float* lnk_b = (const float*)d_in[10];
  const float* lnv_g = (const float*)d_in[11];
  const float* lnv_b = (const float*)d_in[12];

  char* ws = (char*)d_ws;
  u16*   X   = (u16*)  (ws);              // 16777216 B
  u16*   WkT = (u16*)  (ws + 16777216);   // 262144
  u16*   WvT = (u16*)  (ws + 17039360);   // 262144
  float* AM  = (float*)(ws + 17301504);   // 1048576
  float* W4  = (float*)(ws + 18350080);   // 131072
  float* c4  = (float*)(ws + 18481152);   // 1024
  float* tmp = (float*)(ws + 18482176);   // 1048576
  u16*   W4T = (u16*)  (ws + 19530752);   // 65536

  hipMemsetAsync(ws + 17301504, 0, 1180672, stream); // AM, W4, c4

  hipLaunchKernelGGL(kprep, dim3(2048), dim3(256), 0, stream, v, Wk_w, Wv_w, X, WkT, WvT);

  (void)hipFuncSetAttribute((const void*)kattn,
                            hipFuncAttributeMaxDynamicSharedMemorySize, 131072);
  hipLaunchKernelGGL(kattn, dim3(512), dim3(256), 131072, stream,
                     X, WkT, WvT, Wk_b, Wv_b, lnk_g, lnk_b, lnv_g, lnv_b, AM);

  hipLaunchKernelGGL(kfold1, dim3(16), dim3(256), 0, stream, AM, Wo_w, tmp);
  hipLaunchKernelGGL(kfold2, dim3(16), dim3(256), 0, stream, Wq_w, Wq_b, Wo_b, tmp, W4, c4);
  hipLaunchKernelGGL(kfold3, dim3(128), dim3(256), 0, stream, W4, W4T);

  hipLaunchKernelGGL(kout, dim3(512), dim3(256), 65536, stream, X, W4T, c4, (float*)d_out);
}

// Round 2
// 148.036 us; speedup vs baseline: 2.1586x; 2.1586x over previous
//
#include <hip/hip_runtime.h>
#include <stdint.h>

typedef unsigned short u16;
typedef unsigned int u32;
typedef __attribute__((ext_vector_type(8))) short s16x8;
typedef __attribute__((ext_vector_type(8))) __bf16 bf16x8;
typedef __attribute__((ext_vector_type(4))) float f32x4;
typedef __attribute__((ext_vector_type(4))) u16 u16x4;

#define L_TOT 32768
#define NCH 16   // chunks (of 128 rows) per kattn block

__device__ __forceinline__ u32 f2bf(float f){
  u32 u = __builtin_bit_cast(u32, f);
  return (u + 0x7FFFu + ((u >> 16) & 1u)) >> 16;
}
// XOR swizzle: flips byte-addr bits 4-6 with row bits (row stride 256B, 8-row period).
__device__ __forceinline__ u32 swz(u32 a){ return a ^ (((a >> 8) & 7u) << 4); }

__device__ __forceinline__ f32x4 mfma16(s16x8 a, s16x8 b, f32x4 c){
  return __builtin_amdgcn_mfma_f32_16x16x32_bf16(
      __builtin_bit_cast(bf16x8, a), __builtin_bit_cast(bf16x8, b), c, 0, 0, 0);
}

__device__ __forceinline__ void gload16(const void* g, void* l){
  __builtin_amdgcn_global_load_lds(
      (const __attribute__((address_space(1))) void*)g,
      (__attribute__((address_space(3))) void*)l, 16, 0, 0);
}

// packed f32->bf16 (RTNE), lo in [15:0], hi in [31:16]
__device__ __forceinline__ u32 cvtpk(float lo, float hi){
  u32 r;
  asm("v_cvt_pk_bf16_f32 %0, %1, %2" : "=v"(r) : "v"(lo), "v"(hi));
  return r;
}

// all-16-lane sum within each 16-lane group, VALU-only (no LDS pipe)
__device__ __forceinline__ float dpp_reduce16(float x){
  float y;
  asm("v_add_f32_dpp %0, %1, %1 row_ror:8 row_mask:0xf bank_mask:0xf"
      : "=&v"(y) : "v"(x));
  asm("v_add_f32_dpp %0, %1, %1 row_ror:4 row_mask:0xf bank_mask:0xf"
      : "=&v"(x) : "v"(y));
  asm("v_add_f32_dpp %0, %1, %1 quad_perm:[2,3,0,1] row_mask:0xf bank_mask:0xf"
      : "=&v"(y) : "v"(x));
  asm("v_add_f32_dpp %0, %1, %1 quad_perm:[1,0,3,2] row_mask:0xf bank_mask:0xf"
      : "=&v"(x) : "v"(y));
  return x;
}

// ---------------- prep: v -> bf16, Wk/Wv -> transposed bf16 [hd][cin] ----------------
__global__ void kprep(const float* __restrict__ v, const float* __restrict__ Wk,
                      const float* __restrict__ Wv, u16* __restrict__ X,
                      u16* __restrict__ WkT, u16* __restrict__ WvT){
  int tid = blockIdx.x * blockDim.x + threadIdx.x;
  int stride = gridDim.x * blockDim.x;
  for (int i = tid; i < 2097152; i += stride){
    float4 f = *((const float4*)v + i);
    u16x4 o; o.x = (u16)f2bf(f.x); o.y = (u16)f2bf(f.y); o.z = (u16)f2bf(f.z); o.w = (u16)f2bf(f.w);
    *((u16x4*)X + i) = o;
  }
  for (int i = tid; i < 131072; i += stride){
    int n = i >> 7, c = i & 127;
    WkT[i] = (u16)f2bf(Wk[c * 1024 + n]);
    WvT[i] = (u16)f2bf(Wv[c * 1024 + n]);
  }
}

// --------- fused K/V projection + per-head LN + AM += K^T V (per b,h) ---------
// 512 threads: waves 0-3 do K-proj (32 rows each), waves 4-7 do V-proj.
// K^T V: 8 waves tiled 2 (dk64) x 4 (dv32).
__global__ __launch_bounds__(512, 2) void kattn(
    const u16* __restrict__ X, const u16* __restrict__ WkT, const u16* __restrict__ WvT,
    const float* __restrict__ bk, const float* __restrict__ bv,
    const float* __restrict__ gk, const float* __restrict__ bbk,
    const float* __restrict__ gv, const float* __restrict__ bbv,
    float* __restrict__ AM)
{
  extern __shared__ char smem[];
  char* sWk = smem;            // 32 KiB, [dk][c] swizzled
  char* sWv = smem + 32768;
  char* sKT = smem + 65536;    // [dk][l] swizzled
  char* sVT = smem + 98304;    // [dv][l] swizzled

  const int tid = threadIdx.x;
  const int wid = tid >> 6, lane = tid & 63, g = lane >> 4, l15 = lane & 15;
  const int bh = blockIdx.x >> 4, grp = blockIdx.x & 15;
  const int b = bh >> 3, h = bh & 7;
  const bool isK = (wid < 4);
  const int w4 = wid & 3;

  { // stage head weight slices (32 KB each), pre-swizzled source -> linear LDS dest
    const char* gwk = (const char*)(WkT + h * 16384);
    const char* gwv = (const char*)(WvT + h * 16384);
    #pragma unroll
    for (int call = 0; call < 4; ++call){
      u32 o = (u32)(call * 8192 + wid * 1024 + lane * 16);
      gload16(gwk + swz(o), sWk + (call * 8192 + wid * 1024));
      gload16(gwv + swz(o), sWv + (call * 8192 + wid * 1024));
    }
  }
  const float* bias = isK ? bk : bv;
  const float* gam  = isK ? gk : gv;
  const float* beta = isK ? bbk : bbv;
  float br[8], gr[8], betar[8];
  #pragma unroll
  for (int nt = 0; nt < 8; ++nt){
    int idx = h * 128 + nt * 16 + l15;
    br[nt] = bias[idx]; gr[nt] = gam[idx]; betar[nt] = beta[idx];
  }
  asm volatile("s_waitcnt vmcnt(0)" ::: "memory");
  __builtin_amdgcn_s_barrier();

  f32x4 am[4][2];
  #pragma unroll
  for (int mt = 0; mt < 4; ++mt)
    #pragma unroll
    for (int nt = 0; nt < 2; ++nt) am[mt][nt] = f32x4{0.f, 0.f, 0.f, 0.f};

  const u16* Xb = X + (size_t)b * (L_TOT * 128);
  const char* sW = isK ? sWk : sWv;
  char* sT = isK ? sKT : sVT;

  auto pref = [&](s16x8 (&dst)[2][4], int chunk){
    int row0 = (grp * NCH + chunk) * 128;
    #pragma unroll
    for (int mt = 0; mt < 2; ++mt)
      #pragma unroll
      for (int ks = 0; ks < 4; ++ks){
        int r = row0 + w4 * 32 + mt * 16 + l15;
        dst[mt][ks] = *(const s16x8*)(Xb + (size_t)r * 128 + ks * 32 + g * 8);
      }
  };

  auto body = [&](const s16x8 (&af)[2][4]){
    // ---- projection (this wave's proj only) ----
    f32x4 acc[2][8];
    #pragma unroll
    for (int mt = 0; mt < 2; ++mt)
      #pragma unroll
      for (int nt = 0; nt < 8; ++nt) acc[mt][nt] = f32x4{0.f, 0.f, 0.f, 0.f};
    #pragma unroll
    for (int ks = 0; ks < 4; ++ks){
      #pragma unroll
      for (int nt = 0; nt < 8; ++nt){
        u32 a = (u32)((nt * 16 + l15) * 256 + ks * 64 + g * 16);
        s16x8 bfr = *(const s16x8*)(sW + swz(a));
        acc[0][nt] = mfma16(af[0][ks], bfr, acc[0][nt]);
        acc[1][nt] = mfma16(af[1][ks], bfr, acc[1][nt]);
      }
    }
    // ---- LayerNorm + bf16 pack + transposed swizzled store ----
    #pragma unroll
    for (int mt = 0; mt < 2; ++mt){
      #pragma unroll
      for (int j = 0; j < 4; ++j){
        float s = 0.f, q = 0.f;
        float vv[8];
        #pragma unroll
        for (int nt = 0; nt < 8; ++nt){
          float t = acc[mt][nt][j] + br[nt];
          vv[nt] = t; s += t; q += t * t;
        }
        s = dpp_reduce16(s);
        q = dpp_reduce16(q);
        float mean = s * 0.0078125f;
        float var  = q * 0.0078125f - mean * mean;
        float rstd = rsqrtf(var + 1e-5f);
        #pragma unroll
        for (int nt = 0; nt < 8; ++nt)
          acc[mt][nt][j] = (vv[nt] - mean) * rstd * gr[nt] + betar[nt];
      }
      #pragma unroll
      for (int nt = 0; nt < 8; ++nt){
        int dk = nt * 16 + l15;
        int lc = w4 * 32 + mt * 16 + g * 4;
        u32 base = (u32)(dk * 256 + lc * 2);
        uint2 w; w.x = cvtpk(acc[mt][nt][0], acc[mt][nt][1]);
        w.y = cvtpk(acc[mt][nt][2], acc[mt][nt][3]);
        *(uint2*)(sT + swz(base)) = w;
      }
    }
    asm volatile("s_waitcnt lgkmcnt(0)" ::: "memory");
    __builtin_amdgcn_s_barrier();
    asm volatile("" ::: "memory");
    // ---- AM += K^T V ----
    #pragma unroll
    for (int ks2 = 0; ks2 < 4; ++ks2){
      s16x8 a2[4], b2[2];
      #pragma unroll
      for (int mt2 = 0; mt2 < 4; ++mt2){
        int dk = (wid >> 2) * 64 + mt2 * 16 + l15;
        a2[mt2] = *(const s16x8*)(sKT + swz((u32)(dk * 256 + ks2 * 64 + g * 16)));
      }
      #pragma unroll
      for (int nt2 = 0; nt2 < 2; ++nt2){
        int dv = w4 * 32 + nt2 * 16 + l15;
        b2[nt2] = *(const s16x8*)(sVT + swz((u32)(dv * 256 + ks2 * 64 + g * 16)));
      }
      #pragma unroll
      for (int mt2 = 0; mt2 < 4; ++mt2)
        #pragma unroll
        for (int nt2 = 0; nt2 < 2; ++nt2)
          am[mt2][nt2] = mfma16(a2[mt2], b2[nt2], am[mt2][nt2]);
    }
    __builtin_amdgcn_s_barrier();
    asm volatile("" ::: "memory");
  };

  s16x8 af[2][4], afn[2][4];
  pref(af, 0);
  for (int it2 = 0; it2 < NCH; it2 += 2){
    pref(afn, it2 + 1);
    body(af);
    pref(af, (it2 + 2 < NCH) ? it2 + 2 : it2);  // last pref reads dummy rows (unused)
    body(afn);
  }

  float* AMbh = AM + (size_t)bh * 16384;
  #pragma unroll
  for (int mt2 = 0; mt2 < 4; ++mt2)
    #pragma unroll
    for (int nt2 = 0; nt2 < 2; ++nt2)
      #pragma unroll
      for (int j = 0; j < 4; ++j){
        int dk = (wid >> 2) * 64 + mt2 * 16 + g * 4 + j;
        int dv = w4 * 32 + nt2 * 16 + l15;
        atomicAdd(AMbh + dk * 128 + dv, am[mt2][nt2][j]);
      }
}

// --------- merged fold: tmp = AM_bh @ Wo_h ; W4 += Wq_h @ tmp /n ; c4 bias ---------
// grid: 16 (b,h) x 4 e-slices of 32. LDS: sA [128][129] f32 + sS [128][33] f32.
__global__ __launch_bounds__(256) void kfold(
    const float* __restrict__ AM, const float* __restrict__ Wo,
    const float* __restrict__ Wq, const float* __restrict__ Wq_b,
    const float* __restrict__ Wo_b,
    float* __restrict__ W4, float* __restrict__ c4)
{
  extern __shared__ float fsm[];
  float* sA = fsm;               // [128][129]
  float* sS = fsm + 128 * 129;   // [128][33]  (Wo-slice, then tmp-slice)
  int blk = blockIdx.x;
  int bh = blk >> 2, eq = blk & 3;
  int b = bh >> 3, hs = bh & 7;
  int tid = threadIdx.x;

  for (int idx = tid; idx < 16384; idx += 256){
    int r = idx >> 7, c = idx & 127;
    sA[r * 129 + c] = AM[(size_t)bh * 16384 + idx];
  }
  for (int idx = tid; idx < 4096; idx += 256){
    int r = idx >> 5, c = idx & 31;
    sS[r * 33 + c] = Wo[(size_t)hs * 16384 + r * 128 + eq * 32 + c];
  }
  __syncthreads();

  int r0 = (tid >> 4) * 8, e0 = (tid & 15) * 2;
  float t8[8][2] = {};
  for (int c = 0; c < 128; ++c){
    float wv0 = sS[c * 33 + e0], wv1 = sS[c * 33 + e0 + 1];
    #pragma unroll
    for (int i = 0; i < 8; ++i){
      float a = sA[(r0 + i) * 129 + c];
      t8[i][0] += a * wv0; t8[i][1] += a * wv1;
    }
  }
  __syncthreads();
  #pragma unroll
  for (int i = 0; i < 8; ++i){
    sS[(r0 + i) * 33 + e0]     = t8[i][0];
    sS[(r0 + i) * 33 + e0 + 1] = t8[i][1];
  }
  for (int idx = tid; idx < 16384; idx += 256){
    int r = idx >> 7, c = idx & 127;
    sA[r * 129 + c] = Wq[(size_t)r * 1024 + hs * 128 + c];
  }
  __syncthreads();

  float a8[8][2] = {};
  for (int d = 0; d < 128; ++d){
    float t0 = sS[d * 33 + e0], t1 = sS[d * 33 + e0 + 1];
    #pragma unroll
    for (int i = 0; i < 8; ++i){
      float w = sA[(r0 + i) * 129 + d];
      a8[i][0] += w * t0; a8[i][1] += w * t1;
    }
  }
  const float inv_n = 0.0009765625f; // 1/1024
  #pragma unroll
  for (int i = 0; i < 8; ++i){
    atomicAdd(W4 + (size_t)b * 16384 + (r0 + i) * 128 + eq * 32 + e0,     a8[i][0] * inv_n);
    atomicAdd(W4 + (size_t)b * 16384 + (r0 + i) * 128 + eq * 32 + e0 + 1, a8[i][1] * inv_n);
  }
  if (tid < 32){
    float s = 0.f;
    for (int d = 0; d < 128; ++d) s += Wq_b[hs * 128 + d] * sS[d * 33 + tid];
    if (hs == 0) s += Wo_b[eq * 32 + tid];
    atomicAdd(c4 + b * 128 + eq * 32 + tid, s * inv_n);
  }
}

__global__ void kfold3(const float* __restrict__ W4, u16* __restrict__ W4T){
  int i = blockIdx.x * 256 + threadIdx.x;
  if (i >= 32768) return;
  int b = i >> 14, r = i & 16383, e = r >> 7, c = r & 127;
  W4T[i] = (u16)f2bf(W4[(size_t)b * 16384 + c * 128 + e]);
}

// ---------------- out = x @ W4[b] + c4[b] ----------------
__global__ __launch_bounds__(256, 2) void kout(
    const u16* __restrict__ X, const u16* __restrict__ W4T,
    const float* __restrict__ c4, float* __restrict__ out)
{
  extern __shared__ char smem[];
  char* sX = smem; char* sW = smem + 32768;
  int tid = threadIdx.x, wid = tid >> 6, lane = tid & 63, g = lane >> 4, l15 = lane & 15;
  int blk = blockIdx.x; int b = blk >> 8, ch = blk & 255;
  const char* gx = (const char*)(X + ((size_t)b * L_TOT + ch * 128) * 128);
  const char* gw = (const char*)(W4T + (size_t)b * 16384);
  #pragma unroll
  for (int call = 0; call < 8; ++call){
    u32 o = (u32)(call * 4096 + wid * 1024 + lane * 16);
    gload16(gx + swz(o), sX + (call * 4096 + wid * 1024));
    gload16(gw + swz(o), sW + (call * 4096 + wid * 1024));
  }
  asm volatile("s_waitcnt vmcnt(0)" ::: "memory");
  __syncthreads();

  f32x4 acc[2][8];
  #pragma unroll
  for (int mt = 0; mt < 2; ++mt)
    #pragma unroll
    for (int nt = 0; nt < 8; ++nt) acc[mt][nt] = f32x4{0.f, 0.f, 0.f, 0.f};

  #pragma unroll
  for (int ks = 0; ks < 4; ++ks){
    s16x8 a0, a1;
    {
      int r = wid * 32 + l15;
      a0 = *(const s16x8*)(sX + swz((u32)(r * 256 + ks * 64 + g * 16)));
      a1 = *(const s16x8*)(sX + swz((u32)((r + 16) * 256 + ks * 64 + g * 16)));
    }
    #pragma unroll
    for (int nt = 0; nt < 8; ++nt){
      int e = nt * 16 + l15;
      s16x8 bfr = *(const s16x8*)(sW + swz((u32)(e * 256 + ks * 64 + g * 16)));
      acc[0][nt] = mfma16(a0, bfr, acc[0][nt]);
      acc[1][nt] = mfma16(a1, bfr, acc[1][nt]);
    }
  }
  float* ob = out + ((size_t)b * L_TOT + ch * 128) * 128;
  #pragma unroll
  for (int nt = 0; nt < 8; ++nt){
    float c4v = c4[b * 128 + nt * 16 + l15];
    #pragma unroll
    for (int mt = 0; mt < 2; ++mt)
      #pragma unroll
      for (int j = 0; j < 4; ++j){
        int r = wid * 32 + mt * 16 + g * 4 + j;
        ob[r * 128 + nt * 16 + l15] = acc[mt][nt][j] + c4v;
      }
  }
}

extern "C" void kernel_launch(void* const* d_in, const int* in_sizes, int n_in,
                              void* d_out, int out_size, void* d_ws, size_t ws_size,
                              hipStream_t stream){
  const float* v    = (const float*)d_in[0];
  const float* Wq_w = (const float*)d_in[1];
  const float* Wq_b = (const float*)d_in[2];
  const float* Wk_w = (const float*)d_in[3];
  const float* Wk_b = (const float*)d_in[4];
  const float* Wv_w = (const float*)d_in[5];
  const float* Wv_b = (const float*)d_in[6];
  const float* Wo_w = (const float*)d_in[7];
  const float* Wo_b = (const float*)d_in[8];
  const float* lnk_g = (const float*)d_in[9];
  const float* lnk_b = (const float*)d_in[10];
  const float* lnv_g = (const float*)d_in[11];
  const float* lnv_b = (const float*)d_in[12];

  char* ws = (char*)d_ws;
  u16*   X   = (u16*)  (ws);              // 16777216 B
  u16*   WkT = (u16*)  (ws + 16777216);   // 262144
  u16*   WvT = (u16*)  (ws + 17039360);   // 262144
  float* AM  = (float*)(ws + 17301504);   // 1048576
  float* W4  = (float*)(ws + 18350080);   // 131072
  float* c4  = (float*)(ws + 18481152);   // 1024
  u16*   W4T = (u16*)  (ws + 19530752);   // 65536

  hipMemsetAsync(ws + 17301504, 0, 1180672, stream); // AM, W4, c4

  hipLaunchKernelGGL(kprep, dim3(2048), dim3(256), 0, stream, v, Wk_w, Wv_w, X, WkT, WvT);

  (void)hipFuncSetAttribute((const void*)kattn,
                            hipFuncAttributeMaxDynamicSharedMemorySize, 131072);
  hipLaunchKernelGGL(kattn, dim3(256), dim3(512), 131072, stream,
                     X, WkT, WvT, Wk_b, Wv_b, lnk_g, lnk_b, lnv_g, lnv_b, AM);

  (void)hipFuncSetAttribute((const void*)kfold,
                            hipFuncAttributeMaxDynamicSharedMemorySize, 83968);
  hipLaunchKernelGGL(kfold, dim3(64), dim3(256), 83968, stream,
                     AM, Wo_w, Wq_w, Wq_b, Wo_b, W4, c4);
  hipLaunchKernelGGL(kfold3, dim3(128), dim3(256), 0, stream, W4, W4T);

  hipLaunchKernelGGL(kout, dim3(512), dim3(256), 65536, stream, X, W4T, c4, (float*)d_out);
}

// Round 3
// 143.998 us; speedup vs baseline: 2.2191x; 1.0280x over previous
//
#include <hip/hip_runtime.h>
#include <stdint.h>

typedef unsigned short u16;
typedef unsigned int u32;
typedef __attribute__((ext_vector_type(8))) short s16x8;
typedef __attribute__((ext_vector_type(8))) __bf16 bf16x8;
typedef __attribute__((ext_vector_type(4))) float f32x4;
typedef __attribute__((ext_vector_type(2))) float f32x2;
typedef __attribute__((ext_vector_type(4))) u16 u16x4;

#define L_TOT 32768
#define NCH 16   // 128-row chunks per kattn block

__device__ __forceinline__ u32 f2bf(float f){
  u32 u = __builtin_bit_cast(u32, f);
  return (u + 0x7FFFu + ((u >> 16) & 1u)) >> 16;
}

__device__ __forceinline__ f32x4 mfma16(s16x8 a, s16x8 b, f32x4 c){
  return __builtin_amdgcn_mfma_f32_16x16x32_bf16(
      __builtin_bit_cast(bf16x8, a), __builtin_bit_cast(bf16x8, b), c, 0, 0, 0);
}

__device__ __forceinline__ void gload16(const void* g, void* l){
  __builtin_amdgcn_global_load_lds(
      (const __attribute__((address_space(1))) void*)g,
      (__attribute__((address_space(3))) void*)l, 16, 0, 0);
}

__device__ __forceinline__ u32 cvtpk(float lo, float hi){
  u32 r;
  asm("v_cvt_pk_bf16_f32 %0, %1, %2" : "=v"(r) : "v"(lo), "v"(hi));
  return r;
}

// sum across the 16 lanes of each row-group, VALU-only
__device__ __forceinline__ float dpp_reduce16(float x){
  float y;
  asm("v_add_f32_dpp %0, %1, %1 row_ror:8 row_mask:0xf bank_mask:0xf"
      : "=&v"(y) : "v"(x));
  asm("v_add_f32_dpp %0, %1, %1 row_ror:4 row_mask:0xf bank_mask:0xf"
      : "=&v"(x) : "v"(y));
  asm("v_add_f32_dpp %0, %1, %1 quad_perm:[2,3,0,1] row_mask:0xf bank_mask:0xf"
      : "=&v"(y) : "v"(x));
  asm("v_add_f32_dpp %0, %1, %1 quad_perm:[1,0,3,2] row_mask:0xf bank_mask:0xf"
      : "=&v"(x) : "v"(y));
  return x;
}

// ------- prep: v -> bf16 X; Wk/Wv -> bf16 in MFMA B-fragment order -------
// frag index (u16): o = h*16384 + (nt*4+ks)*512 + lane*8 + e
//   holds W[c = ks*32 + (lane>>4)*8 + e][n_global = h*128 + nt*16 + (lane&15)]
__global__ void kprep(const float* __restrict__ v, const float* __restrict__ Wk,
                      const float* __restrict__ Wv, u16* __restrict__ X,
                      u16* __restrict__ WkF, u16* __restrict__ WvF){
  int tid = blockIdx.x * blockDim.x + threadIdx.x;
  int stride = gridDim.x * blockDim.x;
  for (int i = tid; i < 2097152; i += stride){
    float4 f = *((const float4*)v + i);
    u16x4 o; o.x = (u16)f2bf(f.x); o.y = (u16)f2bf(f.y); o.z = (u16)f2bf(f.z); o.w = (u16)f2bf(f.w);
    *((u16x4*)X + i) = o;
  }
  for (int i = tid; i < 131072; i += stride){
    int e = i & 7, ln = (i >> 3) & 63, ks = (i >> 9) & 3, nt = (i >> 11) & 7, h = i >> 14;
    int c = ks * 32 + (ln >> 4) * 8 + e;
    int n = nt * 16 + (ln & 15);
    int src = c * 1024 + h * 128 + n;
    WkF[i] = (u16)f2bf(Wk[src]);
    WvF[i] = (u16)f2bf(Wv[src]);
  }
}

// --------- fused K/V projection + centered-scale + G += K''^T V'' ---------
// 512 threads: waves 0-3 K-proj (32 rows each), waves 4-7 V-proj.
// LN decomposed: K'' = rstd_k*(K-mu_k); G, kbar, vbar accumulated; gamma/beta in kfold.
__global__ __launch_bounds__(512, 2) void kattn(
    const u16* __restrict__ X, const u16* __restrict__ WkF, const u16* __restrict__ WvF,
    const float* __restrict__ bk, const float* __restrict__ bv,
    float* __restrict__ G, float* __restrict__ KBar, float* __restrict__ VBar)
{
  extern __shared__ char smem[];
  char* sWK = smem;            // 32 KiB K-weight frags
  char* sWV = smem + 32768;    // 32 KiB V-weight frags
  char* sKF = smem + 65536;    // 32 KiB K'' frags [nt][kstep][lane*16]
  char* sVF = smem + 98304;    // 32 KiB V'' frags

  const int tid = threadIdx.x;
  const int wid = tid >> 6, lane = tid & 63, g = lane >> 4, l15 = lane & 15;
  const int bh = blockIdx.x >> 4, grp = blockIdx.x & 15;
  const int b = bh >> 3, h = bh & 7;
  const bool isK = (wid < 4);
  const int w4 = wid & 3;

  { // stage weight frags — linear copy (already fragment-ordered in global)
    const char* gwk = (const char*)(WkF + h * 16384);
    const char* gwv = (const char*)(WvF + h * 16384);
    #pragma unroll
    for (int c = 0; c < 4; ++c){
      u32 o = (u32)(c * 8192 + tid * 16);
      gload16(gwk + o, sWK + o);
      gload16(gwv + o, sWV + o);
    }
  }
  const float* bias = isK ? bk : bv;
  float br[8];
  #pragma unroll
  for (int nt = 0; nt < 8; ++nt) br[nt] = bias[h * 128 + nt * 16 + l15];

  asm volatile("s_waitcnt vmcnt(0)" ::: "memory");
  __builtin_amdgcn_s_barrier();

  const char* sW = isK ? sWK : sWV;
  char* sT = isK ? sKF : sVF;
  const u16* Xb = X + (size_t)b * (L_TOT * 128);

  const u32 wread = (u32)(lane * 16);
  char* stbase = sT + (((g >> 1) * 16 + l15) * 16 + (g & 1) * 8 + w4 * 1024);
  const char* kfbase = sKF + lane * 16;
  const char* vfbase = sVF + lane * 16;
  const char* xlane = (const char*)Xb + (w4 * 32 + l15) * 256 + g * 16;

  f32x4 am[4][2];
  #pragma unroll
  for (int t = 0; t < 4; ++t)
    #pragma unroll
    for (int u2 = 0; u2 < 2; ++u2) am[t][u2] = f32x4{0.f, 0.f, 0.f, 0.f};
  f32x2 kb2[8];
  #pragma unroll
  for (int nt = 0; nt < 8; ++nt) kb2[nt] = f32x2{0.f, 0.f};

#define PREF(dst, it) { \
  const char* p_ = xlane + (size_t)((grp * NCH + (it)) * 128) * 256; \
  _Pragma("unroll") for (int mt_ = 0; mt_ < 2; ++mt_) \
  _Pragma("unroll") for (int ks_ = 0; ks_ < 4; ++ks_) \
    dst[mt_][ks_] = *(const s16x8*)(p_ + mt_ * 4096 + ks_ * 64); }

#define BODY(F) { \
    f32x4 acc[2][8]; \
    _Pragma("unroll") for (int mt = 0; mt < 2; ++mt) \
      _Pragma("unroll") for (int nt = 0; nt < 8; ++nt) acc[mt][nt] = f32x4{0.f,0.f,0.f,0.f}; \
    _Pragma("unroll") for (int ks = 0; ks < 4; ++ks){ \
      _Pragma("unroll") for (int nt = 0; nt < 8; ++nt){ \
        s16x8 wf = *(const s16x8*)(sW + wread + (nt * 4 + ks) * 1024); \
        acc[0][nt] = mfma16(F[0][ks], wf, acc[0][nt]); \
        acc[1][nt] = mfma16(F[1][ks], wf, acc[1][nt]); \
      } \
    } \
    _Pragma("unroll") for (int mt = 0; mt < 2; ++mt){ \
      f32x4 sum = {0.f,0.f,0.f,0.f}, sq = {0.f,0.f,0.f,0.f}; \
      _Pragma("unroll") for (int nt = 0; nt < 8; ++nt){ \
        f32x4 t = acc[mt][nt] + f32x4{br[nt], br[nt], br[nt], br[nt]}; \
        acc[mt][nt] = t; sum += t; sq += t * t; \
      } \
      f32x4 s4, ns4; \
      _Pragma("unroll") for (int j = 0; j < 4; ++j){ \
        float ssum = dpp_reduce16(sum[j]); \
        float ssq  = dpp_reduce16(sq[j]); \
        float mean = ssum * 0.0078125f; \
        float var  = ssq * 0.0078125f - mean * mean; \
        float rstd = rsqrtf(var + 1e-5f); \
        s4[j] = rstd; ns4[j] = -mean * rstd; \
      } \
      _Pragma("unroll") for (int nt = 0; nt < 8; ++nt){ \
        f32x4 t = acc[mt][nt] * s4 + ns4; \
        kb2[nt] += f32x2{t.x, t.y} + f32x2{t.z, t.w}; \
        uint2 w_; w_.x = cvtpk(t.x, t.y); w_.y = cvtpk(t.z, t.w); \
        *(uint2*)(stbase + nt * 4096 + mt * 512) = w_; \
      } \
    } \
    asm volatile("s_waitcnt lgkmcnt(0)" ::: "memory"); \
    __builtin_amdgcn_s_barrier(); \
    { \
      const int dkt = (wid >> 2) * 4; \
      _Pragma("unroll") for (int kk = 0; kk < 4; ++kk){ \
        s16x8 a2[4], b2[2]; \
        _Pragma("unroll") for (int t = 0; t < 4; ++t) \
          a2[t] = *(const s16x8*)(kfbase + (dkt + t) * 4096 + kk * 1024); \
        _Pragma("unroll") for (int u2 = 0; u2 < 2; ++u2) \
          b2[u2] = *(const s16x8*)(vfbase + (w4 * 2 + u2) * 4096 + kk * 1024); \
        _Pragma("unroll") for (int t = 0; t < 4; ++t) \
          _Pragma("unroll") for (int u2 = 0; u2 < 2; ++u2) \
            am[t][u2] = mfma16(a2[t], b2[u2], am[t][u2]); \
      } \
    } \
    __builtin_amdgcn_s_barrier(); \
  }

  s16x8 af[2][4], afn[2][4];
  PREF(af, 0);
  #pragma unroll 1
  for (int it2 = 0; it2 < NCH; it2 += 2){
    PREF(afn, it2 + 1);
    BODY(af);
    PREF(af, (it2 + 2 < NCH) ? it2 + 2 : 0);
    BODY(afn);
  }
#undef BODY
#undef PREF

  float* Gbh = G + (size_t)bh * 16384;
  #pragma unroll
  for (int t = 0; t < 4; ++t)
    #pragma unroll
    for (int u2 = 0; u2 < 2; ++u2)
      #pragma unroll
      for (int j = 0; j < 4; ++j){
        int dk = (wid >> 2) * 64 + t * 16 + g * 4 + j;
        int dv = w4 * 32 + u2 * 16 + l15;
        atomicAdd(Gbh + dk * 128 + dv, am[t][u2][j]);
      }
  float* dstB = (isK ? KBar : VBar) + bh * 128;
  #pragma unroll
  for (int nt = 0; nt < 8; ++nt){
    float kb = kb2[nt].x + kb2[nt].y;
    kb += __shfl_xor(kb, 16);
    kb += __shfl_xor(kb, 32);
    if (g == 0) atomicAdd(dstB + nt * 16 + l15, kb);
  }
}

// --------- fold: AM = corrections(G); tmp = AM@Wo ; W4 += Wq@tmp/n ; c4 ---------
__global__ __launch_bounds__(256) void kfold(
    const float* __restrict__ G, const float* __restrict__ KBar, const float* __restrict__ VBar,
    const float* __restrict__ gk, const float* __restrict__ bbk,
    const float* __restrict__ gv, const float* __restrict__ bbv,
    const float* __restrict__ Wo, const float* __restrict__ Wq,
    const float* __restrict__ Wq_b, const float* __restrict__ Wo_b,
    float* __restrict__ W4, float* __restrict__ c4)
{
  extern __shared__ float fsm[];
  float* sA = fsm;               // [128][129]
  float* sS = fsm + 128 * 129;   // [128][33]
  int blk = blockIdx.x;
  int bh = blk >> 2, eq = blk & 3;
  int b = bh >> 3, hs = bh & 7;
  int tid = threadIdx.x;

  const float* gkh = gk + hs * 128; const float* bkh = bbk + hs * 128;
  const float* gvh = gv + hs * 128; const float* bvh = bbv + hs * 128;
  const float* kbh = KBar + bh * 128; const float* vbh = VBar + bh * 128;

  for (int idx = tid; idx < 16384; idx += 256){
    int r = idx >> 7, c = idx & 127;
    float gg = G[(size_t)bh * 16384 + idx];
    float am = gkh[r] * (gvh[c] * gg + kbh[r] * bvh[c])
             + bkh[r] * (gvh[c] * vbh[c] + 32768.f * bvh[c]);
    sA[r * 129 + c] = am;
  }
  for (int idx = tid; idx < 4096; idx += 256){
    int r = idx >> 5, c = idx & 31;
    sS[r * 33 + c] = Wo[(size_t)hs * 16384 + r * 128 + eq * 32 + c];
  }
  __syncthreads();

  int r0 = (tid >> 4) * 8, e0 = (tid & 15) * 2;
  float t8[8][2] = {};
  for (int c = 0; c < 128; ++c){
    float wv0 = sS[c * 33 + e0], wv1 = sS[c * 33 + e0 + 1];
    #pragma unroll
    for (int i = 0; i < 8; ++i){
      float a = sA[(r0 + i) * 129 + c];
      t8[i][0] += a * wv0; t8[i][1] += a * wv1;
    }
  }
  __syncthreads();
  #pragma unroll
  for (int i = 0; i < 8; ++i){
    sS[(r0 + i) * 33 + e0]     = t8[i][0];
    sS[(r0 + i) * 33 + e0 + 1] = t8[i][1];
  }
  for (int idx = tid; idx < 16384; idx += 256){
    int r = idx >> 7, c = idx & 127;
    sA[r * 129 + c] = Wq[(size_t)r * 1024 + hs * 128 + c];
  }
  __syncthreads();

  float a8[8][2] = {};
  for (int d = 0; d < 128; ++d){
    float t0 = sS[d * 33 + e0], t1 = sS[d * 33 + e0 + 1];
    #pragma unroll
    for (int i = 0; i < 8; ++i){
      float w = sA[(r0 + i) * 129 + d];
      a8[i][0] += w * t0; a8[i][1] += w * t1;
    }
  }
  const float inv_n = 0.0009765625f; // 1/1024
  #pragma unroll
  for (int i = 0; i < 8; ++i){
    atomicAdd(W4 + (size_t)b * 16384 + (r0 + i) * 128 + eq * 32 + e0,     a8[i][0] * inv_n);
    atomicAdd(W4 + (size_t)b * 16384 + (r0 + i) * 128 + eq * 32 + e0 + 1, a8[i][1] * inv_n);
  }
  if (tid < 32){
    float s = 0.f;
    for (int d = 0; d < 128; ++d) s += Wq_b[hs * 128 + d] * sS[d * 33 + tid];
    if (hs == 0) s += Wo_b[eq * 32 + tid];
    atomicAdd(c4 + b * 128 + eq * 32 + tid, s * inv_n);
  }
}

// W4 (f32 [b][c][n]) -> W4T bf16 in B-fragment order
__global__ void kfold3(const float* __restrict__ W4, u16* __restrict__ W4T){
  int i = blockIdx.x * 256 + threadIdx.x;
  if (i >= 32768) return;
  int b = i >> 14, o = i & 16383;
  int e = o & 7, ln = (o >> 3) & 63, ks = (o >> 9) & 3, nt = (o >> 11) & 7;
  int c = ks * 32 + (ln >> 4) * 8 + e;
  int n = nt * 16 + (ln & 15);
  W4T[i] = (u16)f2bf(W4[(size_t)b * 16384 + c * 128 + n]);
}

// ---------------- out = x @ W4[b] + c4[b] ----------------
__global__ __launch_bounds__(256, 4) void kout(
    const u16* __restrict__ X, const u16* __restrict__ W4T,
    const float* __restrict__ c4, float* __restrict__ out)
{
  __shared__ char sW[32768];
  const int tid = threadIdx.x, wid = tid >> 6, lane = tid & 63, g = lane >> 4, l15 = lane & 15;
  const int blk = blockIdx.x, b = blk >> 8, ch = blk & 255;
  {
    const char* gw = (const char*)(W4T + (size_t)b * 16384);
    #pragma unroll
    for (int c = 0; c < 8; ++c){
      u32 o = (u32)(c * 4096 + tid * 16);
      gload16(gw + o, sW + o);
    }
  }
  const char* xr = (const char*)(X + ((size_t)b * L_TOT + ch * 128 + wid * 32 + l15) * 128) + g * 16;
  s16x8 af[2][4];
  #pragma unroll
  for (int mt = 0; mt < 2; ++mt)
    #pragma unroll
    for (int ks = 0; ks < 4; ++ks)
      af[mt][ks] = *(const s16x8*)(xr + mt * 4096 + ks * 64);
  asm volatile("s_waitcnt vmcnt(0)" ::: "memory");
  __builtin_amdgcn_s_barrier();

  f32x4 acc[2][8];
  #pragma unroll
  for (int mt = 0; mt < 2; ++mt)
    #pragma unroll
    for (int nt = 0; nt < 8; ++nt) acc[mt][nt] = f32x4{0.f, 0.f, 0.f, 0.f};

  const u32 wread = (u32)(lane * 16);
  #pragma unroll
  for (int ks = 0; ks < 4; ++ks)
    #pragma unroll
    for (int nt = 0; nt < 8; ++nt){
      s16x8 wf = *(const s16x8*)(sW + wread + (nt * 4 + ks) * 1024);
      acc[0][nt] = mfma16(af[0][ks], wf, acc[0][nt]);
      acc[1][nt] = mfma16(af[1][ks], wf, acc[1][nt]);
    }
  float* ob = out + ((size_t)b * L_TOT + ch * 128 + wid * 32) * 128;
  #pragma unroll
  for (int nt = 0; nt < 8; ++nt){
    float c4v = c4[b * 128 + nt * 16 + l15];
    #pragma unroll
    for (int mt = 0; mt < 2; ++mt)
      #pragma unroll
      for (int j = 0; j < 4; ++j)
        ob[(mt * 16 + g * 4 + j) * 128 + nt * 16 + l15] = acc[mt][nt][j] + c4v;
  }
}

extern "C" void kernel_launch(void* const* d_in, const int* in_sizes, int n_in,
                              void* d_out, int out_size, void* d_ws, size_t ws_size,
                              hipStream_t stream){
  const float* v    = (const float*)d_in[0];
  const float* Wq_w = (const float*)d_in[1];
  const float* Wq_b = (const float*)d_in[2];
  const float* Wk_w = (const float*)d_in[3];
  const float* Wk_b = (const float*)d_in[4];
  const float* Wv_w = (const float*)d_in[5];
  const float* Wv_b = (const float*)d_in[6];
  const float* Wo_w = (const float*)d_in[7];
  const float* Wo_b = (const float*)d_in[8];
  const float* lnk_g = (const float*)d_in[9];
  const float* lnk_b = (const float*)d_in[10];
  const float* lnv_g = (const float*)d_in[11];
  const float* lnv_b = (const float*)d_in[12];

  char* ws = (char*)d_ws;
  u16*   X    = (u16*)  (ws);              // 16777216 B
  u16*   WkF  = (u16*)  (ws + 16777216);   // 262144
  u16*   WvF  = (u16*)  (ws + 17039360);   // 262144
  float* G    = (float*)(ws + 17301504);   // 1048576
  float* KBar = (float*)(ws + 18350080);   // 8192
  float* VBar = (float*)(ws + 18358272);   // 8192
  float* W4   = (float*)(ws + 18366464);   // 131072
  float* c4   = (float*)(ws + 18497536);   // 1024
  u16*   W4T  = (u16*)  (ws + 18498560);   // 65536

  hipMemsetAsync(ws + 17301504, 0, 1197056, stream); // G, KBar, VBar, W4, c4

  hipLaunchKernelGGL(kprep, dim3(2048), dim3(256), 0, stream, v, Wk_w, Wv_w, X, WkF, WvF);

  (void)hipFuncSetAttribute((const void*)kattn,
                            hipFuncAttributeMaxDynamicSharedMemorySize, 131072);
  hipLaunchKernelGGL(kattn, dim3(256), dim3(512), 131072, stream,
                     X, WkF, WvF, Wk_b, Wv_b, G, KBar, VBar);

  (void)hipFuncSetAttribute((const void*)kfold,
                            hipFuncAttributeMaxDynamicSharedMemorySize, 83968);
  hipLaunchKernelGGL(kfold, dim3(64), dim3(256), 83968, stream,
                     G, KBar, VBar, lnk_g, lnk_b, lnv_g, lnv_b,
                     Wo_w, Wq_w, Wq_b, Wo_b, W4, c4);
  hipLaunchKernelGGL(kfold3, dim3(128), dim3(256), 0, stream, W4, W4T);

  hipLaunchKernelGGL(kout, dim3(512), dim3(256), 0, stream, X, W4T, c4, (float*)d_out);
}